// Round 23
// baseline (137.500 us; speedup 1.0000x reference)
//
#include <hip/hip_runtime.h>

// MHA fwd: S=2048 B=2 D=1024 H=16 DH=64.
// cvt(f32->bf16) -> merged QKV gemm (128x128x64, 8 waves) -> merged transposes
// -> attn_part (8-wave blocks, q-tile 256, uniform 6-tile chunks, XCD-clustered)
// -> attn_combine -> gemm_out (128x128x64, 8 waves).

typedef float f32x4 __attribute__((ext_vector_type(4)));
typedef float f32x16 __attribute__((ext_vector_type(16)));
typedef __bf16 bf16x8_t __attribute__((ext_vector_type(8)));
typedef unsigned short ushort8 __attribute__((ext_vector_type(8)));
typedef unsigned int uint4v __attribute__((ext_vector_type(4)));
typedef unsigned int uint2v __attribute__((ext_vector_type(2)));

#define S_LEN 2048
#define BATCH 2
#define DMODEL 1024
#define NHEAD 16
#define DHEAD 64
// 1/sqrt(64) * log2(e): scores feed exp2 directly
#define K_SCALE 0.18033688011112042f
#define NCHUNK 27   // sum over Q=0..7 of ceil((4Q+4)/6)

__device__ __forceinline__ unsigned short f2bf(float x) {
  unsigned int u = __builtin_bit_cast(unsigned int, x);
  u += 0x7fffu + ((u >> 16) & 1u);  // RNE
  return (unsigned short)(u >> 16);
}

__device__ __forceinline__ f32x4 mfma16(ushort8 a, ushort8 b, f32x4 c) {
  return __builtin_amdgcn_mfma_f32_16x16x32_bf16(
      __builtin_bit_cast(bf16x8_t, a), __builtin_bit_cast(bf16x8_t, b), c, 0, 0, 0);
}
__device__ __forceinline__ f32x16 mfma32(ushort8 a, ushort8 b, f32x16 c) {
  return __builtin_amdgcn_mfma_f32_32x32x16_bf16(
      __builtin_bit_cast(bf16x8_t, a), __builtin_bit_cast(bf16x8_t, b), c, 0, 0, 0);
}

__device__ __forceinline__ float max3f(float a, float b, float c) {
  return fmaxf(fmaxf(a, b), c);  // clang fuses to v_max3_f32
}

__device__ __forceinline__ ushort8 pack8(float4 a, float4 b, float s) {
  ushort8 t;
  t[0] = f2bf(a.x * s); t[1] = f2bf(a.y * s); t[2] = f2bf(a.z * s); t[3] = f2bf(a.w * s);
  t[4] = f2bf(b.x * s); t[5] = f2bf(b.y * s); t[6] = f2bf(b.z * s); t[7] = f2bf(b.w * s);
  return t;
}

__device__ __forceinline__ void gload16(unsigned short* lds, const unsigned short* g) {
  __builtin_amdgcn_global_load_lds(
      (const __attribute__((address_space(1))) unsigned int*)g,
      (__attribute__((address_space(3))) unsigned int*)lds, 16, 0, 0);
}

// ---------------- f32 -> bf16 bulk convert (7 tensors) ----------------
__global__ __launch_bounds__(256) void cvt_kernel(
    const float* __restrict__ q, const float* __restrict__ k, const float* __restrict__ v,
    const float* __restrict__ wq, const float* __restrict__ wk,
    const float* __restrict__ wv, const float* __restrict__ wo,
    unsigned short* __restrict__ qB, unsigned short* __restrict__ kB,
    unsigned short* __restrict__ vB, unsigned short* __restrict__ wqB,
    unsigned short* __restrict__ wkB, unsigned short* __restrict__ wvB,
    unsigned short* __restrict__ woB)
{
  const int c = blockIdx.x * 256 + threadIdx.x;
  const float* s; unsigned short* d; int base;
  if      (c < 524288)  { s = q;  d = qB;  base = 0; }
  else if (c < 1048576) { s = k;  d = kB;  base = 524288; }
  else if (c < 1572864) { s = v;  d = vB;  base = 1048576; }
  else if (c < 1703936) { s = wq; d = wqB; base = 1572864; }
  else if (c < 1835008) { s = wk; d = wkB; base = 1703936; }
  else if (c < 1966080) { s = wv; d = wvB; base = 1835008; }
  else                  { s = wo; d = woB; base = 1966080; }
  const size_t off = (size_t)(c - base) * 8;
  const float4 v0 = *reinterpret_cast<const float4*>(s + off);
  const float4 v1 = *reinterpret_cast<const float4*>(s + off + 4);
  *reinterpret_cast<ushort8*>(d + off) = pack8(v0, v1, 1.0f);
}

// ------- merged QKV bf16 GEMM (z = 0:Q, 1:K, 2:V), BM=128 BN=128 BK=64, 8 waves -------
__global__ __launch_bounds__(512) void gemm_qkv_kernel(
    const unsigned short* __restrict__ qA, const unsigned short* __restrict__ kA,
    const unsigned short* __restrict__ vA,
    const unsigned short* __restrict__ wqW, const unsigned short* __restrict__ wkW,
    const unsigned short* __restrict__ wvW,
    const float* __restrict__ bq, const float* __restrict__ bk,
    const float* __restrict__ bv,
    unsigned short* __restrict__ Cq, unsigned short* __restrict__ Ck,
    unsigned short* __restrict__ Cv)
{
  __shared__ __align__(16) unsigned short As[2][128 * 64];
  __shared__ __align__(16) unsigned short Ws[2][128 * 64];
  const int z = blockIdx.z;
  const unsigned short* A = (z == 0) ? qA : (z == 1) ? kA : vA;
  const unsigned short* W = (z == 0) ? wqW : (z == 1) ? wkW : wvW;
  const float* bias = (z == 0) ? bq : (z == 1) ? bk : bv;
  unsigned short* C = (z == 0) ? Cq : (z == 1) ? Ck : Cv;
  const float oscale = (z == 1) ? K_SCALE : 1.0f;

  const int tid = threadIdx.x;          // 0..511
  const int lane = tid & 63;
  const int w = tid >> 6;               // 0..7 (2m x 4n)
  const int wm = (w >> 2) * 64, wn = (w & 3) * 32;
  const int g = lane >> 4, lr = lane & 15;

  const int bid = (int)blockIdx.x;      // 256 blocks: 8 n x 32 m
  const int widx = (bid & 7) * 32 + (bid >> 3);
  const int n0 = (widx & 7) * 128;
  const int m0 = (widx >> 3) * 128;

  f32x4 acc[4][2] = {};

#define STAGE(buf, k0)                                                              \
  {                                                                                 \
    _Pragma("unroll")                                                               \
    for (int ii = 0; ii < 2; ++ii) {                                                \
      const int c = ii * 512 + tid;                                                 \
      const int row = c >> 3;                                                       \
      const int sl = (c & 7) ^ (row & 7);                                           \
      gload16(&As[buf][c * 8], A + (size_t)(m0 + row) * DMODEL + (k0) + sl * 8);    \
    }                                                                               \
    _Pragma("unroll")                                                               \
    for (int ii = 0; ii < 2; ++ii) {                                                \
      const int c = ii * 512 + tid;                                                 \
      const int row = c >> 3;                                                       \
      const int sl = (c & 7) ^ (row & 7);                                           \
      gload16(&Ws[buf][c * 8], W + (size_t)(n0 + row) * DMODEL + (k0) + sl * 8);    \
    }                                                                               \
  }

  STAGE(0, 0);
  int cur = 0;

  for (int t = 0; t < 16; ++t) {
    __syncthreads();
    if (t < 15) STAGE(cur ^ 1, (t + 1) * 64);

    const char* ab = (const char*)&As[cur][0];
    const char* wb = (const char*)&Ws[cur][0];
#pragma unroll
    for (int kk = 0; kk < 2; ++kk) {
      ushort8 af[4], bw[2];
#pragma unroll
      for (int mt = 0; mt < 4; ++mt) {
        const int row = wm + mt * 16 + lr;
        af[mt] = *reinterpret_cast<const ushort8*>(
            ab + row * 128 + (((kk * 4 + g) ^ (row & 7)) << 4));
      }
#pragma unroll
      for (int nt = 0; nt < 2; ++nt) {
        const int row = wn + nt * 16 + lr;
        bw[nt] = *reinterpret_cast<const ushort8*>(
            wb + row * 128 + (((kk * 4 + g) ^ (row & 7)) << 4));
      }
      __builtin_amdgcn_s_setprio(1);
#pragma unroll
      for (int mt = 0; mt < 4; ++mt)
#pragma unroll
        for (int nt = 0; nt < 2; ++nt)
          acc[mt][nt] = mfma16(af[mt], bw[nt], acc[mt][nt]);
      __builtin_amdgcn_s_setprio(0);
    }
    cur ^= 1;
  }
#undef STAGE

#pragma unroll
  for (int nt = 0; nt < 2; ++nt) {
    const int col = n0 + wn + nt * 16 + lr;
    const float bvv = bias[col];
#pragma unroll
    for (int mt = 0; mt < 4; ++mt)
#pragma unroll
      for (int r = 0; r < 4; ++r) {
        const int rowg = m0 + wm + mt * 16 + g * 4 + r;
        C[(size_t)rowg * DMODEL + col] = f2bf((acc[mt][nt][r] + bvv) * oscale);
      }
  }
}

// ---------------- out-proj bf16 GEMM (f32 out), BM=128 BN=128 BK=64, 8 waves ----------
__global__ __launch_bounds__(512) void gemm_out_kernel(
    const unsigned short* __restrict__ A, const unsigned short* __restrict__ W,
    const float* __restrict__ bias, float* __restrict__ C)
{
  __shared__ __align__(16) unsigned short As[2][128 * 64];
  __shared__ __align__(16) unsigned short Ws[2][128 * 64];
  const int tid = threadIdx.x;          // 0..511
  const int lane = tid & 63;
  const int w = tid >> 6;               // 0..7 (2m x 4n)
  const int wm = (w >> 2) * 64, wn = (w & 3) * 32;
  const int g = lane >> 4, lr = lane & 15;

  const int bid = (int)blockIdx.x;      // 256 blocks: 8 n x 32 m
  const int widx = (bid & 7) * 32 + (bid >> 3);
  const int n0 = (widx & 7) * 128;
  const int m0 = (widx >> 3) * 128;

  f32x4 acc[4][2] = {};

#define STAGE(buf, k0)                                                              \
  {                                                                                 \
    _Pragma("unroll")                                                               \
    for (int ii = 0; ii < 2; ++ii) {                                                \
      const int c = ii * 512 + tid;                                                 \
      const int row = c >> 3;                                                       \
      const int sl = (c & 7) ^ (row & 7);                                           \
      gload16(&As[buf][c * 8], A + (size_t)(m0 + row) * DMODEL + (k0) + sl * 8);    \
    }                                                                               \
    _Pragma("unroll")                                                               \
    for (int ii = 0; ii < 2; ++ii) {                                                \
      const int c = ii * 512 + tid;                                                 \
      const int row = c >> 3;                                                       \
      const int sl = (c & 7) ^ (row & 7);                                           \
      gload16(&Ws[buf][c * 8], W + (size_t)(n0 + row) * DMODEL + (k0) + sl * 8);    \
    }                                                                               \
  }

  STAGE(0, 0);
  int cur = 0;

  for (int t = 0; t < 16; ++t) {
    __syncthreads();
    if (t < 15) STAGE(cur ^ 1, (t + 1) * 64);

    const char* ab = (const char*)&As[cur][0];
    const char* wb = (const char*)&Ws[cur][0];
#pragma unroll
    for (int kk = 0; kk < 2; ++kk) {
      ushort8 af[4], bw[2];
#pragma unroll
      for (int mt = 0; mt < 4; ++mt) {
        const int row = wm + mt * 16 + lr;
        af[mt] = *reinterpret_cast<const ushort8*>(
            ab + row * 128 + (((kk * 4 + g) ^ (row & 7)) << 4));
      }
#pragma unroll
      for (int nt = 0; nt < 2; ++nt) {
        const int row = wn + nt * 16 + lr;
        bw[nt] = *reinterpret_cast<const ushort8*>(
            wb + row * 128 + (((kk * 4 + g) ^ (row & 7)) << 4));
      }
      __builtin_amdgcn_s_setprio(1);
#pragma unroll
      for (int mt = 0; mt < 4; ++mt)
#pragma unroll
        for (int nt = 0; nt < 2; ++nt)
          acc[mt][nt] = mfma16(af[mt], bw[nt], acc[mt][nt]);
      __builtin_amdgcn_s_setprio(0);
    }
    cur ^= 1;
  }
#undef STAGE

#pragma unroll
  for (int nt = 0; nt < 2; ++nt) {
    const int col = n0 + wn + nt * 16 + lr;
    const float bvv = bias[col];
#pragma unroll
    for (int mt = 0; mt < 4; ++mt)
#pragma unroll
      for (int r = 0; r < 4; ++r) {
        const int rowg = m0 + wm + mt * 16 + g * 4 + r;
        C[(size_t)rowg * DMODEL + col] = acc[mt][nt][r] + bvv;
      }
  }
}

// -------- merged transposes: blocks 0..511 tr0(in0->out0), 512..1023 tr0(in1->out1),
//          1024..2047 tr1(in2->out2). tr0: [n][d*16+h]->[b][h][s][d]; tr1: ->[b][h][d][s].
__global__ __launch_bounds__(256) void transpose_all_kernel(
    const unsigned short* __restrict__ in0, unsigned short* __restrict__ out0,
    const unsigned short* __restrict__ in1, unsigned short* __restrict__ out1,
    const unsigned short* __restrict__ in2, unsigned short* __restrict__ out2)
{
  __shared__ __align__(16) unsigned short T[32 * 256];  // 16KB (tr1 uses 8KB)
  const int bx = (int)blockIdx.x;
  const int tid = threadIdx.x;

  if (bx < 1024) {
    const unsigned short* in = (bx < 512) ? in0 : in1;
    unsigned short* out = (bx < 512) ? out0 : out1;
    const int lb = bx & 511;
    const int n0 = (lb & 127) * 32, o0 = (lb >> 7) * 256;
#pragma unroll
    for (int i = 0; i < 4; ++i) {
      const int c = i * 256 + tid;
      const int row = c >> 5, c8 = c & 31;
      ushort8 v = *reinterpret_cast<const ushort8*>(in + (size_t)(n0 + row) * DMODEL + o0 + c8 * 8);
      int y = (row * 512 + c8 * 16) ^ ((row & 3) << 5);
      *reinterpret_cast<ushort8*>((char*)T + y) = v;
    }
    __syncthreads();
    const int d0 = o0 >> 4, s0 = n0 >> 1;
#pragma unroll
    for (int rep = 0; rep < 2; ++rep) {
      const int e = rep * 256 + tid;
      const int hh = e & 15, s = (e >> 4) & 15, b = (e >> 8) & 1;
      const int n = s * 2 + b;
      unsigned short vals[16];
#pragma unroll
      for (int dd = 0; dd < 16; ++dd) {
        int y = n * 512 + ((dd * 32 + hh * 2) ^ ((n & 3) << 5));
        vals[dd] = *(const unsigned short*)((const char*)T + y);
      }
      uint4v w0, w1;
#pragma unroll
      for (int j = 0; j < 4; ++j) {
        w0[j] = (unsigned)vals[2 * j] | ((unsigned)vals[2 * j + 1] << 16);
        w1[j] = (unsigned)vals[8 + 2 * j] | ((unsigned)vals[8 + 2 * j + 1] << 16);
      }
      unsigned short* dst = out + ((size_t)(b * 16 + hh) * S_LEN + s0 + s) * DHEAD + d0;
      *reinterpret_cast<uint4v*>(dst) = w0;
      *reinterpret_cast<uint4v*>(dst + 8) = w1;
    }
  } else {
    const int lb = bx - 1024;
    const int n0 = (lb & 63) * 64, o0 = (lb >> 6) * 64;
#pragma unroll
    for (int i = 0; i < 2; ++i) {
      const int c = i * 256 + tid;
      const int row = c >> 3, c8 = c & 7;
      ushort8 v = *reinterpret_cast<const ushort8*>(in2 + (size_t)(n0 + row) * DMODEL + o0 + c8 * 8);
      int y = (row * 128 + c8 * 16) ^ ((row & 7) << 4);
      *reinterpret_cast<ushort8*>((char*)T + y) = v;
    }
    __syncthreads();
    const int d0 = o0 >> 4, s0 = n0 >> 1;
    const int shalf = tid & 1, seg = tid >> 1;
    const int dd = seg & 3, hh = (seg >> 2) & 15, b = (seg >> 6) & 1;
    unsigned short vals[16];
#pragma unroll
    for (int i = 0; i < 16; ++i) {
      const int s = shalf * 16 + i;
      const int n = s * 2 + b;
      int y = n * 128 + (((dd * 16 + hh) * 2) ^ ((n & 7) << 4));
      vals[i] = *(const unsigned short*)((const char*)T + y);
    }
    uint4v w0, w1;
#pragma unroll
    for (int j = 0; j < 4; ++j) {
      w0[j] = (unsigned)vals[2 * j] | ((unsigned)vals[2 * j + 1] << 16);
      w1[j] = (unsigned)vals[8 + 2 * j] | ((unsigned)vals[8 + 2 * j + 1] << 16);
    }
    unsigned short* dst = out2 + ((size_t)(b * 16 + hh) * DHEAD + d0 + dd) * S_LEN + s0 + shalf * 16;
    *reinterpret_cast<uint4v*>(dst) = w0;
    *reinterpret_cast<uint4v*>(dst + 8) = w1;
  }
}

// ---------------- attn part (K-split flash, causal), 8 waves, q-tile 256 ----------------
// Qh,Kh: [b][h][s][64] bf16 (K pre-scaled). Vh: [b][h][d][s] bf16.
// grid 864 (1D, XCD head-clustered); 8 waves, q-tile 256, uniform 6-tile chunks.
// nch(Q) = ceil((4Q+4)/6); NCHUNK = 27.
__global__ __launch_bounds__(512) void attn_part_kernel(
    const unsigned short* __restrict__ Qh, const unsigned short* __restrict__ Kh,
    const unsigned short* __restrict__ Vh, unsigned short* __restrict__ Opart,
    float* __restrict__ mlbuf)
{
  __shared__ __align__(16) unsigned short Ks[2][64 * 64];  // [key][d] swizzled
  __shared__ __align__(16) unsigned short Vs[2][64 * 64];  // [d][key] swizzled

  const int tid = threadIdx.x;   // 0..511
  const int lane = tid & 63;
  const int w = tid >> 6;        // 0..7
  const int ln31 = lane & 31;
  const int hf = lane >> 5;

  const int bid = (int)blockIdx.x;
  const int xcd = bid & 7;
  const int sl8 = bid >> 3;          // 0..107
  const int hb = xcd * 4 + sl8 / NCHUNK;
  const int chunkid = sl8 % NCHUNK;

  // decode chunk -> (Q, c): nch(Q) = (4Q+9)/6
  int u = chunkid;
  int Q = 0, nc = 1;
  while (u >= nc) { u -= nc; ++Q; nc = (4 * Q + 9) / 6; }
  const int c = u;

  const int head = hb & 15, b = hb >> 4;
  const int slot = hb * NCHUNK + chunkid;
  const int t0 = c * 6;
  const int tmax = 4 * Q + 3;
  const int t1 = (tmax < t0 + 5) ? tmax : (t0 + 5);  // inclusive
  const int q0 = Q * 256;

  const size_t hoff = (size_t)(b * NHEAD + head) * (S_LEN * DHEAD);
  const unsigned short* Qg = Qh + hoff;
  const unsigned short* Kg = Kh + hoff;
  const unsigned short* Vg = Vh + hoff;

  const int qwb = q0 + w * 32;      // wave q base
  const int qg = qwb + ln31;        // this lane's q

  ushort8 qf[4];
#pragma unroll
  for (int kt = 0; kt < 4; ++kt)
    qf[kt] = *reinterpret_cast<const ushort8*>(Qg + (size_t)qg * DHEAD + kt * 16 + hf * 8);

  f32x16 oa0 = {0}, oa1 = {0};
  float mrun = -1e30f, ssum = 0.f;

  // staging with 512 threads: exactly 1 K chunk + 1 V chunk per thread
#define STAGE(buf, kv)                                                             \
  {                                                                                \
    const int row = tid >> 3;                                                      \
    const int sl = (tid & 7) ^ (row & 7);                                          \
    gload16(&Ks[buf][tid * 8], Kg + (size_t)((kv) + row) * 64 + sl * 8);           \
    gload16(&Vs[buf][tid * 8], Vg + (size_t)row * S_LEN + (kv) + sl * 8);          \
  }

  STAGE(0, t0 * 64);
  int cur = 0;

  const int kb0 = ln31 * 128 + ((hf * 16) ^ ((ln31 & 7) << 4));
  const int kb1 = (32 + ln31) * 128 + ((hf * 16) ^ ((ln31 & 7) << 4));

  for (int t = t0; t <= t1; ++t) {
    const int kv0 = t * 64;
    __syncthreads();                       // tile t resident (drains vmcnt)
    if (t < t1) STAGE(cur ^ 1, kv0 + 64);

    if (kv0 <= qwb + 31) {                 // wave has live keys in this tile
      // ---- QK^T ----
      f32x16 sc0 = {0}, sc1 = {0};
      {
        const char* ksb = (const char*)&Ks[cur][0];
        __builtin_amdgcn_s_setprio(1);
#pragma unroll
        for (int kt = 0; kt < 4; ++kt) {
          ushort8 kf0 = *reinterpret_cast<const ushort8*>(ksb + (kb0 ^ (kt << 5)));
          ushort8 kf1 = *reinterpret_cast<const ushort8*>(ksb + (kb1 ^ (kt << 5)));
          sc0 = mfma32(kf0, qf[kt], sc0);
          sc1 = mfma32(kf1, qf[kt], sc1);
        }
        __builtin_amdgcn_s_setprio(0);
      }

      // ---- causal mask (tiles crossing this wave's diagonal) ----
      if (kv0 + 63 > qwb) {
#pragma unroll
        for (int r = 0; r < 16; ++r) {
          const int keyb = kv0 + (r & 3) + 8 * (r >> 2) + 4 * hf;
          if (keyb > qg) sc0[r] = -1e30f;
          if (keyb + 32 > qg) sc1[r] = -1e30f;
        }
      }

      // ---- max via v_max3 tree ----
      float m0a = max3f(sc0[0], sc0[1], sc0[2]);
      float m1a = max3f(sc0[3], sc0[4], sc0[5]);
      float m2a = max3f(sc0[6], sc0[7], sc0[8]);
      float m3a = max3f(sc0[9], sc0[10], sc0[11]);
      float m4a = max3f(sc0[12], sc0[13], sc0[14]);
      float m5a = max3f(sc0[15], sc1[0], sc1[1]);
      float m6a = max3f(sc1[2], sc1[3], sc1[4]);
      float m7a = max3f(sc1[5], sc1[6], sc1[7]);
      float m8a = max3f(sc1[8], sc1[9], sc1[10]);
      float m9a = max3f(sc1[11], sc1[12], sc1[13]);
      float mAa = fmaxf(sc1[14], sc1[15]);
      float n0a = max3f(m0a, m1a, m2a);
      float n1a = max3f(m3a, m4a, m5a);
      float n2a = max3f(m6a, m7a, m8a);
      float n3a = fmaxf(m9a, mAa);
      float pmax = fmaxf(max3f(n0a, n1a, n2a), n3a);
      pmax = fmaxf(pmax, __shfl_xor(pmax, 32, 64));

      if (!__all(pmax <= mrun + 8.0f)) {  // defer-max (T13)
        const float mnew = fmaxf(mrun, pmax);
        const float scl = exp2f(mrun - mnew);
        ssum *= scl;
#pragma unroll
        for (int r = 0; r < 16; ++r) { oa0[r] *= scl; oa1[r] *= scl; }
        mrun = mnew;
      }

      float pv0[16], pv1[16];
#pragma unroll
      for (int r = 0; r < 16; ++r) {
        pv0[r] = exp2f(sc0[r] - mrun);
        pv1[r] = exp2f(sc1[r] - mrun);
      }
      // pairwise sum tree
      float a8[8];
#pragma unroll
      for (int r = 0; r < 8; ++r)
        a8[r] = (pv0[r] + pv0[r + 8]) + (pv1[r] + pv1[r + 8]);
      float a4_0 = a8[0] + a8[4], a4_1 = a8[1] + a8[5];
      float a4_2 = a8[2] + a8[6], a4_3 = a8[3] + a8[7];
      float psum = (a4_0 + a4_1) + (a4_2 + a4_3);
      psum += __shfl_xor(psum, 32, 64);
      ssum += psum;

      // ---- P -> bf16 B-frags (cvt_pk + permlane32_swap) ----
      unsigned int cc[16];
#pragma unroll
      for (int j = 0; j < 8; ++j) {
        asm("v_cvt_pk_bf16_f32 %0, %1, %2" : "=v"(cc[j]) : "v"(pv0[2 * j]), "v"(pv0[2 * j + 1]));
        asm("v_cvt_pk_bf16_f32 %0, %1, %2" : "=v"(cc[8 + j]) : "v"(pv1[2 * j]), "v"(pv1[2 * j + 1]));
      }

      uint4v pfw[4];
#pragma unroll
      for (int mt = 0; mt < 2; ++mt) {
#pragma unroll
        for (int ktl = 0; ktl < 2; ++ktl) {
          const int o = mt * 8 + ktl * 4;
          unsigned x0 = cc[o + 0], x2 = cc[o + 2];
          unsigned y0 = cc[o + 1], y2 = cc[o + 3];
          asm("v_permlane32_swap_b32 %0, %1" : "+v"(x0), "+v"(x2));
          asm("v_permlane32_swap_b32 %0, %1" : "+v"(y0), "+v"(y2));
          uint4v u4;
          u4[0] = x0; u4[1] = y0; u4[2] = x2; u4[3] = y2;
          pfw[mt * 2 + ktl] = u4;
        }
      }

      // ---- PV ----
      {
        const char* vsb = (const char*)&Vs[cur][0];
        __builtin_amdgcn_s_setprio(1);
#pragma unroll
        for (int kt = 0; kt < 4; ++kt) {
          ushort8 vf0 = *reinterpret_cast<const ushort8*>(vsb + (kb0 ^ (kt << 5)));
          ushort8 vf1 = *reinterpret_cast<const ushort8*>(vsb + (kb1 ^ (kt << 5)));
          ushort8 pfr = __builtin_bit_cast(ushort8, pfw[kt]);
          oa0 = mfma32(vf0, pfr, oa0);
          oa1 = mfma32(vf1, pfr, oa1);
        }
        __builtin_amdgcn_s_setprio(0);
      }
    }

    cur ^= 1;
  }
#undef STAGE

  // ---- epilogue: unnormalized partial O (bf16) + (m, l) ----
  const int ql = w * 32 + ln31;  // local q row 0..255
  unsigned short* ob = Opart + (size_t)slot * 16384 + ql * 64;
#pragma unroll
  for (int mt2 = 0; mt2 < 2; ++mt2) {
#pragma unroll
    for (int rq = 0; rq < 4; ++rq) {
      const int dd = mt2 * 32 + 8 * rq + 4 * hf;
      const f32x16& a = mt2 ? oa1 : oa0;
      unsigned int w0, w1;
      asm("v_cvt_pk_bf16_f32 %0, %1, %2" : "=v"(w0)
          : "v"(a[4 * rq + 0]), "v"(a[4 * rq + 1]));
      asm("v_cvt_pk_bf16_f32 %0, %1, %2" : "=v"(w1)
          : "v"(a[4 * rq + 2]), "v"(a[4 * rq + 3]));
      uint2v pk = { w0, w1 };
      *reinterpret_cast<uint2v*>(ob + dd) = pk;
    }
  }
  if (hf == 0) {
    mlbuf[slot * 512 + ql] = mrun;
    mlbuf[slot * 512 + 256 + ql] = ssum;
  }
}

// ---------------- attn combine: merge <=6 chunks per (hb, Q) ----------------
// grid (8, 32), 512 threads: q = tid>>1 (0..255), dh = (tid&1)*32.
__global__ __launch_bounds__(512) void attn_combine_kernel(
    const unsigned short* __restrict__ Opart, const float* __restrict__ mlbuf,
    unsigned short* __restrict__ O)
{
  const int Q = blockIdx.x, hb = blockIdx.y;
  const int head = hb & 15, b = hb >> 4;
  const int nch = (4 * Q + 9) / 6;
  int off = 0;
  for (int j = 0; j < Q; ++j) off += (4 * j + 9) / 6;
  const int s0 = hb * NCHUNK + off;

  const int tid = threadIdx.x;
  const int q = tid >> 1, dh = (tid & 1) * 32;

  float mc[6], lc[6];
  float M = -1e30f;
  for (int cc = 0; cc < nch; ++cc) {
    mc[cc] = mlbuf[(s0 + cc) * 512 + q];
    lc[cc] = mlbuf[(s0 + cc) * 512 + 256 + q];
    M = fmaxf(M, mc[cc]);
  }
  float L = 0.f, wgt[6];
  for (int cc = 0; cc < nch; ++cc) {
    wgt[cc] = exp2f(mc[cc] - M);
    L += wgt[cc] * lc[cc];
  }
  const float invL = 1.0f / L;

  float acc[32] = {};
  for (int cc = 0; cc < nch; ++cc) {
    const unsigned short* p = Opart + (size_t)(s0 + cc) * 16384 + q * 64 + dh;
    const float wv = wgt[cc];
#pragma unroll
    for (int seg = 0; seg < 4; ++seg) {
      ushort8 v = *reinterpret_cast<const ushort8*>(p + seg * 8);
#pragma unroll
      for (int j = 0; j < 8; ++j) {
        const float f = __builtin_bit_cast(float, ((unsigned int)v[j]) << 16);
        acc[seg * 8 + j] += wv * f;
      }
    }
  }

  unsigned int wpk[16];
#pragma unroll
  for (int j = 0; j < 16; ++j) {
    asm("v_cvt_pk_bf16_f32 %0, %1, %2" : "=v"(wpk[j])
        : "v"(acc[2 * j] * invL), "v"(acc[2 * j + 1] * invL));
  }
  unsigned short* dst = O + ((size_t)((Q * 256 + q) * BATCH + b)) * DMODEL + head * DHEAD + dh;
#pragma unroll
  for (int seg = 0; seg < 4; ++seg)
    *reinterpret_cast<uint4v*>(dst + seg * 8) =
        uint4v{ wpk[4 * seg], wpk[4 * seg + 1], wpk[4 * seg + 2], wpk[4 * seg + 3] };
}

extern "C" void kernel_launch(void* const* d_in, const int* in_sizes, int n_in,
                              void* d_out, int out_size, void* d_ws, size_t ws_size,
                              hipStream_t stream)
{
  (void)in_sizes; (void)n_in; (void)out_size; (void)ws_size;
  const float* query = (const float*)d_in[0];
  const float* key_  = (const float*)d_in[1];
  const float* value = (const float*)d_in[2];
  // d_in[3] = mask: exactly causal, handled analytically.
  const float* Wq = (const float*)d_in[4];
  const float* bq = (const float*)d_in[5];
  const float* Wk = (const float*)d_in[6];
  const float* bk = (const float*)d_in[7];
  const float* Wv = (const float*)d_in[8];
  const float* bv = (const float*)d_in[9];
  const float* Wo = (const float*)d_in[10];
  const float* bo = (const float*)d_in[11];
  float* out = (float*)d_out;

  const size_t NE = (size_t)4096 * DMODEL;
  const size_t NW = (size_t)DMODEL * DMODEL;
  unsigned short* qB  = (unsigned short*)d_ws;  // Q bf16 in; later Q-head final; later combine out
  unsigned short* kB  = qB + NE;                // K bf16 in; later V-head final [b][h][d][s]
  unsigned short* vB  = kB + NE;                // V bf16 in; later Opart overlay base
  unsigned short* g1  = vB + NE;                // Pq (Q proj out)
  unsigned short* Qh  = g1 + NE;                // Pk (K proj out)
  unsigned short* Kh  = Qh + NE;                // Pv (V proj out)
  unsigned short* Vh  = Kh + NE;                // K-head final [b][h][s][64]
  unsigned short* wqB = Vh + NE;
  unsigned short* wkB = wqB + NW;
  unsigned short* wvB = wkB + NW;
  unsigned short* woB = wvB + NW;
  // Opart overlays vB,g1,Qh,Kh (all dead by attn time): 27*32 slots * 32KB = 27.0MB
  // + mlbuf 1.8MB = 28.8MB <= 33.6MB dead span (Vh untouched).
  unsigned short* Opart = vB;
  float* mlbuf = (float*)(Opart + (size_t)(NCHUNK * 32) * 16384);

  cvt_kernel<<<dim3(8192), 256, 0, stream>>>(query, key_, value, Wq, Wk, Wv, Wo,
                                             qB, kB, vB, wqB, wkB, wvB, woB);
  // Pq=g1, Pk=Qh, Pv=Kh  (BM=128 BN=128, 256 blocks/z, 512 threads)
  gemm_qkv_kernel<<<dim3(256, 1, 3), 512, 0, stream>>>(
      qB, kB, vB, wqB, wkB, wvB, bq, bk, bv, g1, Qh, Kh);
  // g1 -> qB (Q head-major); Qh -> Vh (K head-major); Kh -> kB (V d-major)
  transpose_all_kernel<<<dim3(2048), 256, 0, stream>>>(g1, qB, Qh, Vh, Kh, kB);
  attn_part_kernel<<<dim3(NCHUNK * 32), 512, 0, stream>>>(qB, Vh, kB, Opart, mlbuf);
  attn_combine_kernel<<<dim3(8, 32), 512, 0, stream>>>(Opart, mlbuf, qB);
  gemm_out_kernel<<<dim3(256), 512, 0, stream>>>(qB, woB, bo, out);
}

// Round 24
// 132.664 us; speedup vs baseline: 1.0365x; 1.0365x over previous
//
#include <hip/hip_runtime.h>

// MHA fwd: S=2048 B=2 D=1024 H=16 DH=64.  (Best-measured config = round 21, 133.0 us.)
// cvt(f32->bf16) -> merged QKV gemm (128x128x64, 8 waves) -> merged transposes
// -> attn_part (uniform 6-tile chunks, XCD head-clustered, permlane P-exchange)
// -> attn_combine -> gemm_out.

typedef float f32x4 __attribute__((ext_vector_type(4)));
typedef float f32x16 __attribute__((ext_vector_type(16)));
typedef __bf16 bf16x8_t __attribute__((ext_vector_type(8)));
typedef unsigned short ushort8 __attribute__((ext_vector_type(8)));
typedef unsigned int uint4v __attribute__((ext_vector_type(4)));
typedef unsigned int uint2v __attribute__((ext_vector_type(2)));

#define S_LEN 2048
#define BATCH 2
#define DMODEL 1024
#define NHEAD 16
#define DHEAD 64
// 1/sqrt(64) * log2(e): scores feed exp2 directly
#define K_SCALE 0.18033688011112042f
#define NCHUNK 51   // sum over Q of (Q/3+1)

__device__ __forceinline__ unsigned short f2bf(float x) {
  unsigned int u = __builtin_bit_cast(unsigned int, x);
  u += 0x7fffu + ((u >> 16) & 1u);  // RNE
  return (unsigned short)(u >> 16);
}

__device__ __forceinline__ f32x4 mfma16(ushort8 a, ushort8 b, f32x4 c) {
  return __builtin_amdgcn_mfma_f32_16x16x32_bf16(
      __builtin_bit_cast(bf16x8_t, a), __builtin_bit_cast(bf16x8_t, b), c, 0, 0, 0);
}
__device__ __forceinline__ f32x16 mfma32(ushort8 a, ushort8 b, f32x16 c) {
  return __builtin_amdgcn_mfma_f32_32x32x16_bf16(
      __builtin_bit_cast(bf16x8_t, a), __builtin_bit_cast(bf16x8_t, b), c, 0, 0, 0);
}

__device__ __forceinline__ float max3f(float a, float b, float c) {
  return fmaxf(fmaxf(a, b), c);  // clang fuses to v_max3_f32
}

__device__ __forceinline__ ushort8 pack8(float4 a, float4 b, float s) {
  ushort8 t;
  t[0] = f2bf(a.x * s); t[1] = f2bf(a.y * s); t[2] = f2bf(a.z * s); t[3] = f2bf(a.w * s);
  t[4] = f2bf(b.x * s); t[5] = f2bf(b.y * s); t[6] = f2bf(b.z * s); t[7] = f2bf(b.w * s);
  return t;
}

__device__ __forceinline__ void gload16(unsigned short* lds, const unsigned short* g) {
  __builtin_amdgcn_global_load_lds(
      (const __attribute__((address_space(1))) unsigned int*)g,
      (__attribute__((address_space(3))) unsigned int*)lds, 16, 0, 0);
}

// ---------------- f32 -> bf16 bulk convert (7 tensors) ----------------
__global__ __launch_bounds__(256) void cvt_kernel(
    const float* __restrict__ q, const float* __restrict__ k, const float* __restrict__ v,
    const float* __restrict__ wq, const float* __restrict__ wk,
    const float* __restrict__ wv, const float* __restrict__ wo,
    unsigned short* __restrict__ qB, unsigned short* __restrict__ kB,
    unsigned short* __restrict__ vB, unsigned short* __restrict__ wqB,
    unsigned short* __restrict__ wkB, unsigned short* __restrict__ wvB,
    unsigned short* __restrict__ woB)
{
  const int c = blockIdx.x * 256 + threadIdx.x;
  const float* s; unsigned short* d; int base;
  if      (c < 524288)  { s = q;  d = qB;  base = 0; }
  else if (c < 1048576) { s = k;  d = kB;  base = 524288; }
  else if (c < 1572864) { s = v;  d = vB;  base = 1048576; }
  else if (c < 1703936) { s = wq; d = wqB; base = 1572864; }
  else if (c < 1835008) { s = wk; d = wkB; base = 1703936; }
  else if (c < 1966080) { s = wv; d = wvB; base = 1835008; }
  else                  { s = wo; d = woB; base = 1966080; }
  const size_t off = (size_t)(c - base) * 8;
  const float4 v0 = *reinterpret_cast<const float4*>(s + off);
  const float4 v1 = *reinterpret_cast<const float4*>(s + off + 4);
  *reinterpret_cast<ushort8*>(d + off) = pack8(v0, v1, 1.0f);
}

// ------- merged QKV bf16 GEMM (z = 0:Q, 1:K, 2:V), BM=128 BN=128 BK=64, 8 waves -------
__global__ __launch_bounds__(512) void gemm_qkv_kernel(
    const unsigned short* __restrict__ qA, const unsigned short* __restrict__ kA,
    const unsigned short* __restrict__ vA,
    const unsigned short* __restrict__ wqW, const unsigned short* __restrict__ wkW,
    const unsigned short* __restrict__ wvW,
    const float* __restrict__ bq, const float* __restrict__ bk,
    const float* __restrict__ bv,
    unsigned short* __restrict__ Cq, unsigned short* __restrict__ Ck,
    unsigned short* __restrict__ Cv)
{
  __shared__ __align__(16) unsigned short As[2][128 * 64];
  __shared__ __align__(16) unsigned short Ws[2][128 * 64];
  const int z = blockIdx.z;
  const unsigned short* A = (z == 0) ? qA : (z == 1) ? kA : vA;
  const unsigned short* W = (z == 0) ? wqW : (z == 1) ? wkW : wvW;
  const float* bias = (z == 0) ? bq : (z == 1) ? bk : bv;
  unsigned short* C = (z == 0) ? Cq : (z == 1) ? Ck : Cv;
  const float oscale = (z == 1) ? K_SCALE : 1.0f;

  const int tid = threadIdx.x;          // 0..511
  const int lane = tid & 63;
  const int w = tid >> 6;               // 0..7 (2m x 4n)
  const int wm = (w >> 2) * 64, wn = (w & 3) * 32;
  const int g = lane >> 4, lr = lane & 15;

  // 256 blocks/z: 8 n-blocks x 32 m-blocks; XCD-bijective swizzle
  const int bid = (int)blockIdx.x;
  const int widx = (bid & 7) * 32 + (bid >> 3);
  const int n0 = (widx & 7) * 128;
  const int m0 = (widx >> 3) * 128;

  f32x4 acc[4][2] = {};

#define STAGE(buf, k0)                                                              \
  {                                                                                 \
    _Pragma("unroll")                                                               \
    for (int ii = 0; ii < 2; ++ii) {                                                \
      const int c = ii * 512 + tid;                                                 \
      const int row = c >> 3;                                                       \
      const int sl = (c & 7) ^ (row & 7);                                           \
      gload16(&As[buf][c * 8], A + (size_t)(m0 + row) * DMODEL + (k0) + sl * 8);    \
    }                                                                               \
    _Pragma("unroll")                                                               \
    for (int ii = 0; ii < 2; ++ii) {                                                \
      const int c = ii * 512 + tid;                                                 \
      const int row = c >> 3;                                                       \
      const int sl = (c & 7) ^ (row & 7);                                           \
      gload16(&Ws[buf][c * 8], W + (size_t)(n0 + row) * DMODEL + (k0) + sl * 8);    \
    }                                                                               \
  }

  STAGE(0, 0);
  int cur = 0;

  for (int t = 0; t < 16; ++t) {
    __syncthreads();
    if (t < 15) STAGE(cur ^ 1, (t + 1) * 64);

    const char* ab = (const char*)&As[cur][0];
    const char* wb = (const char*)&Ws[cur][0];
#pragma unroll
    for (int kk = 0; kk < 2; ++kk) {
      ushort8 af[4], bw[2];
#pragma unroll
      for (int mt = 0; mt < 4; ++mt) {
        const int row = wm + mt * 16 + lr;
        af[mt] = *reinterpret_cast<const ushort8*>(
            ab + row * 128 + (((kk * 4 + g) ^ (row & 7)) << 4));
      }
#pragma unroll
      for (int nt = 0; nt < 2; ++nt) {
        const int row = wn + nt * 16 + lr;
        bw[nt] = *reinterpret_cast<const ushort8*>(
            wb + row * 128 + (((kk * 4 + g) ^ (row & 7)) << 4));
      }
      __builtin_amdgcn_s_setprio(1);
#pragma unroll
      for (int mt = 0; mt < 4; ++mt)
#pragma unroll
        for (int nt = 0; nt < 2; ++nt)
          acc[mt][nt] = mfma16(af[mt], bw[nt], acc[mt][nt]);
      __builtin_amdgcn_s_setprio(0);
    }
    cur ^= 1;
  }
#undef STAGE

#pragma unroll
  for (int nt = 0; nt < 2; ++nt) {
    const int col = n0 + wn + nt * 16 + lr;
    const float bvv = bias[col];
#pragma unroll
    for (int mt = 0; mt < 4; ++mt)
#pragma unroll
      for (int r = 0; r < 4; ++r) {
        const int rowg = m0 + wm + mt * 16 + g * 4 + r;
        C[(size_t)rowg * DMODEL + col] = f2bf((acc[mt][nt][r] + bvv) * oscale);
      }
  }
}

// ---------------- out-proj bf16 GEMM (f32 out) ----------------
__global__ __launch_bounds__(256) void gemm_out_kernel(
    const unsigned short* __restrict__ A, const unsigned short* __restrict__ W,
    const float* __restrict__ bias, float* __restrict__ C)
{
  __shared__ __align__(16) unsigned short As[2][128 * 64];
  __shared__ __align__(16) unsigned short Ws[2][64 * 64];
  const int tid = threadIdx.x;
  const int lane = tid & 63;
  const int w = tid >> 6;
  const int wm = (w >> 1) * 64, wn = (w & 1) * 32;
  const int g = lane >> 4, lr = lane & 15;

  const int bid = (int)blockIdx.x;
  const int widx = (bid & 7) * 64 + (bid >> 3);
  const int n0 = (widx & 15) * 64;
  const int m0 = (widx >> 4) * 128;

  f32x4 acc[4][2] = {};

#define STAGE(buf, k0)                                                              \
  {                                                                                 \
    _Pragma("unroll")                                                               \
    for (int ii = 0; ii < 4; ++ii) {                                                \
      const int c = ii * 256 + tid;                                                 \
      const int row = c >> 3;                                                       \
      const int sl = (c & 7) ^ (row & 7);                                           \
      gload16(&As[buf][c * 8], A + (size_t)(m0 + row) * DMODEL + (k0) + sl * 8);    \
    }                                                                               \
    _Pragma("unroll")                                                               \
    for (int ii = 0; ii < 2; ++ii) {                                                \
      const int c = ii * 256 + tid;                                                 \
      const int row = c >> 3;                                                       \
      const int sl = (c & 7) ^ (row & 7);                                           \
      gload16(&Ws[buf][c * 8], W + (size_t)(n0 + row) * DMODEL + (k0) + sl * 8);    \
    }                                                                               \
  }

  STAGE(0, 0);
  int cur = 0;

  for (int t = 0; t < 16; ++t) {
    __syncthreads();
    if (t < 15) STAGE(cur ^ 1, (t + 1) * 64);

    const char* ab = (const char*)&As[cur][0];
    const char* wb = (const char*)&Ws[cur][0];
#pragma unroll
    for (int kk = 0; kk < 2; ++kk) {
      ushort8 af[4], bw[2];
#pragma unroll
      for (int mt = 0; mt < 4; ++mt) {
        const int row = wm + mt * 16 + lr;
        af[mt] = *reinterpret_cast<const ushort8*>(
            ab + row * 128 + (((kk * 4 + g) ^ (row & 7)) << 4));
      }
#pragma unroll
      for (int nt = 0; nt < 2; ++nt) {
        const int row = wn + nt * 16 + lr;
        bw[nt] = *reinterpret_cast<const ushort8*>(
            wb + row * 128 + (((kk * 4 + g) ^ (row & 7)) << 4));
      }
      __builtin_amdgcn_s_setprio(1);
#pragma unroll
      for (int mt = 0; mt < 4; ++mt)
#pragma unroll
        for (int nt = 0; nt < 2; ++nt)
          acc[mt][nt] = mfma16(af[mt], bw[nt], acc[mt][nt]);
      __builtin_amdgcn_s_setprio(0);
    }
    cur ^= 1;
  }
#undef STAGE

#pragma unroll
  for (int nt = 0; nt < 2; ++nt) {
    const int col = n0 + wn + nt * 16 + lr;
    const float bvv = bias[col];
#pragma unroll
    for (int mt = 0; mt < 4; ++mt)
#pragma unroll
      for (int r = 0; r < 4; ++r) {
        const int rowg = m0 + wm + mt * 16 + g * 4 + r;
        C[(size_t)rowg * DMODEL + col] = acc[mt][nt][r] + bvv;
      }
  }
}

// -------- merged transposes: blocks 0..511 tr0(in0->out0), 512..1023 tr0(in1->out1),
//          1024..2047 tr1(in2->out2). tr0: [n][d*16+h]->[b][h][s][d]; tr1: ->[b][h][d][s].
__global__ __launch_bounds__(256) void transpose_all_kernel(
    const unsigned short* __restrict__ in0, unsigned short* __restrict__ out0,
    const unsigned short* __restrict__ in1, unsigned short* __restrict__ out1,
    const unsigned short* __restrict__ in2, unsigned short* __restrict__ out2)
{
  __shared__ __align__(16) unsigned short T[32 * 256];  // 16KB (tr1 uses 8KB)
  const int bx = (int)blockIdx.x;
  const int tid = threadIdx.x;

  if (bx < 1024) {
    const unsigned short* in = (bx < 512) ? in0 : in1;
    unsigned short* out = (bx < 512) ? out0 : out1;
    const int lb = bx & 511;
    const int n0 = (lb & 127) * 32, o0 = (lb >> 7) * 256;
#pragma unroll
    for (int i = 0; i < 4; ++i) {
      const int c = i * 256 + tid;
      const int row = c >> 5, c8 = c & 31;
      ushort8 v = *reinterpret_cast<const ushort8*>(in + (size_t)(n0 + row) * DMODEL + o0 + c8 * 8);
      int y = (row * 512 + c8 * 16) ^ ((row & 3) << 5);
      *reinterpret_cast<ushort8*>((char*)T + y) = v;
    }
    __syncthreads();
    const int d0 = o0 >> 4, s0 = n0 >> 1;
#pragma unroll
    for (int rep = 0; rep < 2; ++rep) {
      const int e = rep * 256 + tid;
      const int hh = e & 15, s = (e >> 4) & 15, b = (e >> 8) & 1;
      const int n = s * 2 + b;
      unsigned short vals[16];
#pragma unroll
      for (int dd = 0; dd < 16; ++dd) {
        int y = n * 512 + ((dd * 32 + hh * 2) ^ ((n & 3) << 5));
        vals[dd] = *(const unsigned short*)((const char*)T + y);
      }
      uint4v w0, w1;
#pragma unroll
      for (int j = 0; j < 4; ++j) {
        w0[j] = (unsigned)vals[2 * j] | ((unsigned)vals[2 * j + 1] << 16);
        w1[j] = (unsigned)vals[8 + 2 * j] | ((unsigned)vals[8 + 2 * j + 1] << 16);
      }
      unsigned short* dst = out + ((size_t)(b * 16 + hh) * S_LEN + s0 + s) * DHEAD + d0;
      *reinterpret_cast<uint4v*>(dst) = w0;
      *reinterpret_cast<uint4v*>(dst + 8) = w1;
    }
  } else {
    const int lb = bx - 1024;
    const int n0 = (lb & 63) * 64, o0 = (lb >> 6) * 64;
#pragma unroll
    for (int i = 0; i < 2; ++i) {
      const int c = i * 256 + tid;
      const int row = c >> 3, c8 = c & 7;
      ushort8 v = *reinterpret_cast<const ushort8*>(in2 + (size_t)(n0 + row) * DMODEL + o0 + c8 * 8);
      int y = (row * 128 + c8 * 16) ^ ((row & 7) << 4);
      *reinterpret_cast<ushort8*>((char*)T + y) = v;
    }
    __syncthreads();
    const int d0 = o0 >> 4, s0 = n0 >> 1;
    const int shalf = tid & 1, seg = tid >> 1;
    const int dd = seg & 3, hh = (seg >> 2) & 15, b = (seg >> 6) & 1;
    unsigned short vals[16];
#pragma unroll
    for (int i = 0; i < 16; ++i) {
      const int s = shalf * 16 + i;
      const int n = s * 2 + b;
      int y = n * 128 + (((dd * 16 + hh) * 2) ^ ((n & 7) << 4));
      vals[i] = *(const unsigned short*)((const char*)T + y);
    }
    uint4v w0, w1;
#pragma unroll
    for (int j = 0; j < 4; ++j) {
      w0[j] = (unsigned)vals[2 * j] | ((unsigned)vals[2 * j + 1] << 16);
      w1[j] = (unsigned)vals[8 + 2 * j] | ((unsigned)vals[8 + 2 * j + 1] << 16);
    }
    unsigned short* dst = out2 + ((size_t)(b * 16 + hh) * DHEAD + d0 + dd) * S_LEN + s0 + shalf * 16;
    *reinterpret_cast<uint4v*>(dst) = w0;
    *reinterpret_cast<uint4v*>(dst + 8) = w1;
  }
}

// ---------------- attn part (K-split flash, causal) ----------------
// Qh,Kh: [b][h][s][64] bf16 (K pre-scaled). Vh: [b][h][d][s] bf16.
// grid 1632 (1D, XCD head-clustered); 4 waves, q-tile 128, uniform 6-tile chunks.
__global__ __launch_bounds__(256, 4) void attn_part_kernel(
    const unsigned short* __restrict__ Qh, const unsigned short* __restrict__ Kh,
    const unsigned short* __restrict__ Vh, unsigned short* __restrict__ Opart,
    float* __restrict__ mlbuf)
{
  __shared__ __align__(16) unsigned short Ks[2][64 * 64];  // [key][d] swizzled
  __shared__ __align__(16) unsigned short Vs[2][64 * 64];  // [d][key] swizzled

  const int tid = threadIdx.x;
  const int lane = tid & 63;
  const int w = tid >> 6;        // 0..3
  const int ln31 = lane & 31;
  const int hf = lane >> 5;

  const int bid = (int)blockIdx.x;
  const int xcd = bid & 7;
  const int sl8 = bid >> 3;          // 0..203
  const int hb = xcd * 4 + sl8 / NCHUNK;
  const int chunkid = sl8 % NCHUNK;

  int u = chunkid;
  int Q = 0, nc = 1;
  while (u >= nc) { u -= nc; ++Q; nc = Q / 3 + 1; }
  const int c = u;

  const int head = hb & 15, b = hb >> 4;
  const int slot = hb * NCHUNK + chunkid;
  const int t0 = c * 6;
  const int tmax = 2 * Q + 1;
  const int t1 = (tmax < t0 + 5) ? tmax : (t0 + 5);  // inclusive
  const int q0 = Q * 128;

  const size_t hoff = (size_t)(b * NHEAD + head) * (S_LEN * DHEAD);
  const unsigned short* Qg = Qh + hoff;
  const unsigned short* Kg = Kh + hoff;
  const unsigned short* Vg = Vh + hoff;

  const int qwb = q0 + w * 32;      // wave q base
  const int qg = qwb + ln31;        // this lane's q

  ushort8 qf[4];
#pragma unroll
  for (int kt = 0; kt < 4; ++kt)
    qf[kt] = *reinterpret_cast<const ushort8*>(Qg + (size_t)qg * DHEAD + kt * 16 + hf * 8);

  f32x16 oa0 = {0}, oa1 = {0};
  float mrun = -1e30f, ssum = 0.f;

#define STAGE(buf, kv)                                                             \
  {                                                                                \
    _Pragma("unroll")                                                              \
    for (int ii = 0; ii < 2; ++ii) {                                               \
      const int c2 = ii * 256 + tid;                                               \
      const int row = c2 >> 3;                                                     \
      const int sl = (c2 & 7) ^ (row & 7);                                         \
      gload16(&Ks[buf][c2 * 8], Kg + (size_t)((kv) + row) * 64 + sl * 8);          \
    }                                                                              \
    _Pragma("unroll")                                                              \
    for (int ii = 0; ii < 2; ++ii) {                                               \
      const int c2 = ii * 256 + tid;                                               \
      const int row = c2 >> 3;                                                     \
      const int sl = (c2 & 7) ^ (row & 7);                                         \
      gload16(&Vs[buf][c2 * 8], Vg + (size_t)row * S_LEN + (kv) + sl * 8);         \
    }                                                                              \
  }

  STAGE(0, t0 * 64);
  int cur = 0;

  const int kb0 = ln31 * 128 + ((hf * 16) ^ ((ln31 & 7) << 4));
  const int kb1 = (32 + ln31) * 128 + ((hf * 16) ^ ((ln31 & 7) << 4));

  for (int t = t0; t <= t1; ++t) {
    const int kv0 = t * 64;
    __syncthreads();                       // tile t resident (drains vmcnt)
    if (t < t1) STAGE(cur ^ 1, kv0 + 64);

    if (kv0 <= qwb + 31) {                 // wave has live keys in this tile
      // ---- QK^T ----
      f32x16 sc0 = {0}, sc1 = {0};
      {
        const char* ksb = (const char*)&Ks[cur][0];
        __builtin_amdgcn_s_setprio(1);
#pragma unroll
        for (int kt = 0; kt < 4; ++kt) {
          ushort8 kf0 = *reinterpret_cast<const ushort8*>(ksb + (kb0 ^ (kt << 5)));
          ushort8 kf1 = *reinterpret_cast<const ushort8*>(ksb + (kb1 ^ (kt << 5)));
          sc0 = mfma32(kf0, qf[kt], sc0);
          sc1 = mfma32(kf1, qf[kt], sc1);
        }
        __builtin_amdgcn_s_setprio(0);
      }

      // ---- causal mask (tiles crossing this wave's diagonal) ----
      if (kv0 + 63 > qwb) {
#pragma unroll
        for (int r = 0; r < 16; ++r) {
          const int keyb = kv0 + (r & 3) + 8 * (r >> 2) + 4 * hf;
          if (keyb > qg) sc0[r] = -1e30f;
          if (keyb + 32 > qg) sc1[r] = -1e30f;
        }
      }

      // ---- max via v_max3 tree ----
      float m0a = max3f(sc0[0], sc0[1], sc0[2]);
      float m1a = max3f(sc0[3], sc0[4], sc0[5]);
      float m2a = max3f(sc0[6], sc0[7], sc0[8]);
      float m3a = max3f(sc0[9], sc0[10], sc0[11]);
      float m4a = max3f(sc0[12], sc0[13], sc0[14]);
      float m5a = max3f(sc0[15], sc1[0], sc1[1]);
      float m6a = max3f(sc1[2], sc1[3], sc1[4]);
      float m7a = max3f(sc1[5], sc1[6], sc1[7]);
      float m8a = max3f(sc1[8], sc1[9], sc1[10]);
      float m9a = max3f(sc1[11], sc1[12], sc1[13]);
      float mAa = fmaxf(sc1[14], sc1[15]);
      float n0a = max3f(m0a, m1a, m2a);
      float n1a = max3f(m3a, m4a, m5a);
      float n2a = max3f(m6a, m7a, m8a);
      float n3a = fmaxf(m9a, mAa);
      float pmax = fmaxf(max3f(n0a, n1a, n2a), n3a);
      pmax = fmaxf(pmax, __shfl_xor(pmax, 32, 64));

      if (!__all(pmax <= mrun + 8.0f)) {  // defer-max (T13)
        const float mnew = fmaxf(mrun, pmax);
        const float scl = exp2f(mrun - mnew);
        ssum *= scl;
#pragma unroll
        for (int r = 0; r < 16; ++r) { oa0[r] *= scl; oa1[r] *= scl; }
        mrun = mnew;
      }

      float pv0[16], pv1[16];
#pragma unroll
      for (int r = 0; r < 16; ++r) {
        pv0[r] = exp2f(sc0[r] - mrun);
        pv1[r] = exp2f(sc1[r] - mrun);
      }
      // pairwise sum tree
      float a8[8];
#pragma unroll
      for (int r = 0; r < 8; ++r)
        a8[r] = (pv0[r] + pv0[r + 8]) + (pv1[r] + pv1[r + 8]);
      float a4_0 = a8[0] + a8[4], a4_1 = a8[1] + a8[5];
      float a4_2 = a8[2] + a8[6], a4_3 = a8[3] + a8[7];
      float psum = (a4_0 + a4_1) + (a4_2 + a4_3);
      psum += __shfl_xor(psum, 32, 64);
      ssum += psum;

      // ---- P -> bf16 B-frags (cvt_pk + permlane32_swap) ----
      unsigned int cc[16];
#pragma unroll
      for (int j = 0; j < 8; ++j) {
        asm("v_cvt_pk_bf16_f32 %0, %1, %2" : "=v"(cc[j]) : "v"(pv0[2 * j]), "v"(pv0[2 * j + 1]));
        asm("v_cvt_pk_bf16_f32 %0, %1, %2" : "=v"(cc[8 + j]) : "v"(pv1[2 * j]), "v"(pv1[2 * j + 1]));
      }

      uint4v pfw[4];
#pragma unroll
      for (int mt = 0; mt < 2; ++mt) {
#pragma unroll
        for (int ktl = 0; ktl < 2; ++ktl) {
          const int o = mt * 8 + ktl * 4;
          unsigned x0 = cc[o + 0], x2 = cc[o + 2];
          unsigned y0 = cc[o + 1], y2 = cc[o + 3];
          asm("v_permlane32_swap_b32 %0, %1" : "+v"(x0), "+v"(x2));
          asm("v_permlane32_swap_b32 %0, %1" : "+v"(y0), "+v"(y2));
          uint4v u4;
          u4[0] = x0; u4[1] = y0; u4[2] = x2; u4[3] = y2;
          pfw[mt * 2 + ktl] = u4;
        }
      }

      // ---- PV ----
      {
        const char* vsb = (const char*)&Vs[cur][0];
        __builtin_amdgcn_s_setprio(1);
#pragma unroll
        for (int kt = 0; kt < 4; ++kt) {
          ushort8 vf0 = *reinterpret_cast<const ushort8*>(vsb + (kb0 ^ (kt << 5)));
          ushort8 vf1 = *reinterpret_cast<const ushort8*>(vsb + (kb1 ^ (kt << 5)));
          ushort8 pfr = __builtin_bit_cast(ushort8, pfw[kt]);
          oa0 = mfma32(vf0, pfr, oa0);
          oa1 = mfma32(vf1, pfr, oa1);
        }
        __builtin_amdgcn_s_setprio(0);
      }
    }

    cur ^= 1;
  }
#undef STAGE

  // ---- epilogue: unnormalized partial O (bf16) + (m, l) ----
  const int ql = w * 32 + ln31;  // local q row 0..127
  unsigned short* ob = Opart + (size_t)slot * 8192 + ql * 64;
#pragma unroll
  for (int mt2 = 0; mt2 < 2; ++mt2) {
#pragma unroll
    for (int rq = 0; rq < 4; ++rq) {
      const int dd = mt2 * 32 + 8 * rq + 4 * hf;
      const f32x16& a = mt2 ? oa1 : oa0;
      unsigned int w0, w1;
      asm("v_cvt_pk_bf16_f32 %0, %1, %2" : "=v"(w0)
          : "v"(a[4 * rq + 0]), "v"(a[4 * rq + 1]));
      asm("v_cvt_pk_bf16_f32 %0, %1, %2" : "=v"(w1)
          : "v"(a[4 * rq + 2]), "v"(a[4 * rq + 3]));
      uint2v pk = { w0, w1 };
      *reinterpret_cast<uint2v*>(ob + dd) = pk;
    }
  }
  if (hf == 0) {
    mlbuf[slot * 256 + ql] = mrun;
    mlbuf[slot * 256 + 128 + ql] = ssum;
  }
}

// ---------------- attn combine: merge <=6 chunks per (hb, Q) ----------------
__global__ __launch_bounds__(256) void attn_combine_kernel(
    const unsigned short* __restrict__ Opart, const float* __restrict__ mlbuf,
    unsigned short* __restrict__ O)
{
  const int Q = blockIdx.x, hb = blockIdx.y;
  const int head = hb & 15, b = hb >> 4;
  const int nch = Q / 3 + 1;
  int off = 0;
  for (int j = 0; j < Q; ++j) off += j / 3 + 1;
  const int s0 = hb * NCHUNK + off;

  const int tid = threadIdx.x;
  const int q = tid >> 1, dh = (tid & 1) * 32;

  float mc[6], lc[6];
  float M = -1e30f;
  for (int cc = 0; cc < nch; ++cc) {
    mc[cc] = mlbuf[(s0 + cc) * 256 + q];
    lc[cc] = mlbuf[(s0 + cc) * 256 + 128 + q];
    M = fmaxf(M, mc[cc]);
  }
  float L = 0.f, wgt[6];
  for (int cc = 0; cc < nch; ++cc) {
    wgt[cc] = exp2f(mc[cc] - M);
    L += wgt[cc] * lc[cc];
  }
  const float invL = 1.0f / L;

  float acc[32] = {};
  for (int cc = 0; cc < nch; ++cc) {
    const unsigned short* p = Opart + (size_t)(s0 + cc) * 8192 + q * 64 + dh;
    const float wv = wgt[cc];
#pragma unroll
    for (int seg = 0; seg < 4; ++seg) {
      ushort8 v = *reinterpret_cast<const ushort8*>(p + seg * 8);
#pragma unroll
      for (int j = 0; j < 8; ++j) {
        const float f = __builtin_bit_cast(float, ((unsigned int)v[j]) << 16);
        acc[seg * 8 + j] += wv * f;
      }
    }
  }

  unsigned int wpk[16];
#pragma unroll
  for (int j = 0; j < 16; ++j) {
    asm("v_cvt_pk_bf16_f32 %0, %1, %2" : "=v"(wpk[j])
        : "v"(acc[2 * j] * invL), "v"(acc[2 * j + 1] * invL));
  }
  unsigned short* dst = O + ((size_t)((Q * 128 + q) * BATCH + b)) * DMODEL + head * DHEAD + dh;
#pragma unroll
  for (int seg = 0; seg < 4; ++seg)
    *reinterpret_cast<uint4v*>(dst + seg * 8) =
        uint4v{ wpk[4 * seg], wpk[4 * seg + 1], wpk[4 * seg + 2], wpk[4 * seg + 3] };
}

extern "C" void kernel_launch(void* const* d_in, const int* in_sizes, int n_in,
                              void* d_out, int out_size, void* d_ws, size_t ws_size,
                              hipStream_t stream)
{
  (void)in_sizes; (void)n_in; (void)out_size; (void)ws_size;
  const float* query = (const float*)d_in[0];
  const float* key_  = (const float*)d_in[1];
  const float* value = (const float*)d_in[2];
  // d_in[3] = mask: exactly causal, handled analytically.
  const float* Wq = (const float*)d_in[4];
  const float* bq = (const float*)d_in[5];
  const float* Wk = (const float*)d_in[6];
  const float* bk = (const float*)d_in[7];
  const float* Wv = (const float*)d_in[8];
  const float* bv = (const float*)d_in[9];
  const float* Wo = (const float*)d_in[10];
  const float* bo = (const float*)d_in[11];
  float* out = (float*)d_out;

  const size_t NE = (size_t)4096 * DMODEL;
  const size_t NW = (size_t)DMODEL * DMODEL;
  unsigned short* qB  = (unsigned short*)d_ws;  // Q bf16 in; later Q-head final; later combine out
  unsigned short* kB  = qB + NE;                // K bf16 in; later V-head final [b][h][d][s]
  unsigned short* vB  = kB + NE;                // V bf16 in; later Opart overlay base
  unsigned short* g1  = vB + NE;                // Pq (Q proj out)
  unsigned short* Qh  = g1 + NE;                // Pk (K proj out)
  unsigned short* Kh  = Qh + NE;                // Pv (V proj out)
  unsigned short* Vh  = Kh + NE;                // K-head final [b][h][s][64]
  unsigned short* wqB = Vh + NE;
  unsigned short* wkB = wqB + NW;
  unsigned short* wvB = wkB + NW;
  unsigned short* woB = wvB + NW;
  // Opart overlays vB,g1,Qh,Kh (all dead by attn time): 51*32 slots * 16KB = 26.7MB
  // + mlbuf 1.7MB = 28.4MB <= 32MB dead span (Vh untouched).
  unsigned short* Opart = vB;
  float* mlbuf = (float*)(Opart + (size_t)(NCHUNK * 32) * 8192);

  cvt_kernel<<<dim3(8192), 256, 0, stream>>>(query, key_, value, Wq, Wk, Wv, Wo,
                                             qB, kB, vB, wqB, wkB, wvB, woB);
  // Pq=g1, Pk=Qh, Pv=Kh  (BM=128 BN=128, 256 blocks/z, 512 threads)
  gemm_qkv_kernel<<<dim3(256, 1, 3), 512, 0, stream>>>(
      qB, kB, vB, wqB, wkB, wvB, bq, bk, bv, g1, Qh, Kh);
  // g1 -> qB (Q head-major); Qh -> Vh (K head-major); Kh -> kB (V d-major)
  transpose_all_kernel<<<dim3(2048), 256, 0, stream>>>(g1, qB, Qh, Vh, Kh, kB);
  attn_part_kernel<<<dim3(NCHUNK * 32), 256, 0, stream>>>(qB, Vh, kB, Opart, mlbuf);
  attn_combine_kernel<<<dim3(16, 32), 256, 0, stream>>>(Opart, mlbuf, qB);
  gemm_out_kernel<<<dim3(512), 256, 0, stream>>>(qB, woB, bo, out);
}